// Round 5
// baseline (313.946 us; speedup 1.0000x reference)
//
#include <hip/hip_runtime.h>
#include <hip/hip_bf16.h>

typedef __attribute__((ext_vector_type(8))) short bf16x8;
typedef __attribute__((ext_vector_type(4))) float f32x4;
typedef __attribute__((ext_vector_type(4))) unsigned int u32x4;

#define HH 512
#define WWD 512
#define HW (HH * WWD)
#define TW 64
#define HALO_W 66
#define ROWS 18                       // circular slots: 10 read + 8 write, disjoint
#define NPIX (ROWS * HALO_W)          // 1188
#define XBYTES (NPIX * 64)            // 76032
#define NITER 16

__device__ __forceinline__ unsigned short f2bf(float f) {
    unsigned u = __builtin_bit_cast(unsigned, f);
    u += 0x7FFFu + ((u >> 16) & 1u);
    return (unsigned short)(u >> 16);
}

// uniform 40 loads/thread: 2560 units = (g:4) x (hh:8) x (ww:80, 66 real)
__device__ __forceinline__ void issue8(const float* __restrict__ xb, int row0, int w0,
                                       float (&sv)[5][8]) {
    #pragma unroll
    for (int k = 0; k < 5; ++k) {
        int u = threadIdx.x + k * 512;
        int g = u / 640, r = u - g * 640, hh = r / 80, ww = r - hh * 80;
        int wwc = ww < 66 ? ww : 65;
        int row = row0 + hh, cl = w0 + wwc - 1;
        bool ok = (ww < 66) & ((unsigned)row < 512u) & ((unsigned)cl < 512u);
        int rowc = row < 0 ? 0 : (row > 511 ? 511 : row);
        int clc  = cl  < 0 ? 0 : (cl  > 511 ? 511 : cl);
        const float* src = xb + (size_t)(g * 8) * HW + rowc * WWD + clc;
        #pragma unroll
        for (int j = 0; j < 8; ++j) { float v = src[(size_t)j * HW]; sv[k][j] = ok ? v : 0.f; }
    }
}

__device__ __forceinline__ void write8(char* smem, int wsb, float (&sv)[5][8]) {
    #pragma unroll
    for (int k = 0; k < 5; ++k) {
        int u = threadIdx.x + k * 512;
        int g = u / 640, r = u - g * 640, hh = r / 80, ww = r - hh * 80;
        int slot = wsb + hh; if (slot >= ROWS) slot -= ROWS;
        int p = slot * HALO_W + (ww < 66 ? ww : 0);
        int byte = (ww < 66) ? (g * NPIX + p) * 16 : XBYTES;   // dummies -> scratch slot
        unsigned q0 = (unsigned)f2bf(sv[k][0]) | ((unsigned)f2bf(sv[k][1]) << 16);
        unsigned q1 = (unsigned)f2bf(sv[k][2]) | ((unsigned)f2bf(sv[k][3]) << 16);
        unsigned q2 = (unsigned)f2bf(sv[k][4]) | ((unsigned)f2bf(sv[k][5]) << 16);
        unsigned q3 = (unsigned)f2bf(sv[k][6]) | ((unsigned)f2bf(sv[k][7]) << 16);
        u32x4 q = { q0, q1, q2, q3 };
        *(u32x4*)(smem + byte) = q;
    }
}

template<int WAITN, bool ISS, bool WR, bool BAR>
__device__ __forceinline__ void conv_body(char* smem, const float* __restrict__ xb,
                                          float* __restrict__ ob,
                                          bf16x8 (&wf)[9][2],
                                          float (&cur)[5][8], float (&nxt)[5][8],
                                          int srb, int row0, int issrow, int w0,
                                          int wv, int col16, int g4) {
    if (ISS) {
        issue8(xb, issrow, w0, nxt);              // loads(t+2) in flight across barriers
        __builtin_amdgcn_sched_barrier(0);
    }
    if constexpr (WAITN == 40)      asm volatile("s_waitcnt vmcnt(40)" ::: "memory");
    else if constexpr (WAITN == 48) asm volatile("s_waitcnt vmcnt(48)" ::: "memory");
    else if constexpr (WAITN == 8)  asm volatile("s_waitcnt vmcnt(8)"  ::: "memory");
    else                            asm volatile("s_waitcnt vmcnt(63)" ::: "memory");

    if (WR) {   // rows(t+1) -> disjoint slots; interleaves with MFMAs below
        int wsb = srb + 10; if (wsb >= ROWS) wsb -= ROWS;
        write8(smem, wsb, cur);
    }

    f32x4 acc[4][2];
    #pragma unroll
    for (int m = 0; m < 4; ++m) {
        f32x4 z = {0.f, 0.f, 0.f, 0.f};
        acc[m][0] = z; acc[m][1] = z;
    }
    int rs[3];
    #pragma unroll
    for (int dh = 0; dh < 3; ++dh) {
        int s = srb + wv + dh; if (s >= ROWS) s -= ROWS;
        rs[dh] = s * HALO_W;
    }
    const char* xg = smem + g4 * (NPIX * 16);
    #pragma unroll
    for (int dh = 0; dh < 3; ++dh) {
        #pragma unroll
        for (int dw = 0; dw < 3; ++dw) {
            const int tap = dh * 3 + dw;
            #pragma unroll
            for (int m = 0; m < 4; ++m) {
                bf16x8 a = *(const bf16x8*)(xg + (rs[dh] + m * 16 + col16 + dw) * 16);
                acc[m][0] = __builtin_amdgcn_mfma_f32_16x16x32_bf16(a, wf[tap][0], acc[m][0], 0, 0, 0);
                acc[m][1] = __builtin_amdgcn_mfma_f32_16x16x32_bf16(a, wf[tap][1], acc[m][1], 0, 0, 0);
            }
        }
    }
    {
        float* orow = ob + (size_t)(row0 + wv) * WWD + w0;
        #pragma unroll
        for (int m = 0; m < 4; ++m)
            #pragma unroll
            for (int n = 0; n < 2; ++n)
                *(f32x4*)(orow + (size_t)(n * 16 + col16) * HW + m * 16 + g4 * 4) = acc[m][n];
    }
    if (BAR) {
        asm volatile("s_waitcnt lgkmcnt(0)" ::: "memory");
        __builtin_amdgcn_sched_barrier(0);
        __builtin_amdgcn_s_barrier();
        __builtin_amdgcn_sched_barrier(0);
    }
}

__global__ __launch_bounds__(512, 2)
void conv3x3_mfma(const float* __restrict__ x,
                  const float* __restrict__ wk,
                  float* __restrict__ out) {
    __shared__ __align__(16) char smem[XBYTES + 16];   // + dummy scratch slot

    const int tid   = threadIdx.x;
    const int lane  = tid & 63;
    const int wv    = tid >> 6;
    const int col16 = lane & 15;
    const int g4    = lane >> 4;

    const int w0    = blockIdx.x * TW;
    const int hbase = blockIdx.y * (8 * NITER);
    const int b     = blockIdx.z;

    const float* xb = x + (size_t)b * 32 * HW;
    float* ob = out + (size_t)b * 32 * HW;

    // ---- stage weights (f32, padded) into x-LDS temporarily; gather to regs ----
    bf16x8 wf[9][2];
    {
        float* ws = (float*)smem;
        for (int i = tid; i < 9216; i += 512) {
            int oc = i / 288;
            ws[oc * 289 + (i - oc * 288)] = wk[i];
        }
        __syncthreads();
        #pragma unroll
        for (int tap = 0; tap < 9; ++tap) {
            #pragma unroll
            for (int n = 0; n < 2; ++n) {
                bf16x8 f;
                #pragma unroll
                for (int j = 0; j < 8; ++j)
                    f[j] = (short)f2bf(ws[(n * 16 + col16) * 289 + (g4 * 8 + j) * 9 + tap]);
                wf[tap][n] = f;
            }
        }
        __syncthreads();   // gather done before x-fill overwrites
    }

    // ---- prologue fill: rows hbase-1..hbase+8 -> slots 0..9 ----
    {
        float svp[6][8];
        #pragma unroll
        for (int k = 0; k < 6; ++k) {
            int u = tid + k * 512;
            if (u < 2640) {
                int g = u / 660, r = u - g * 660, hh = r / 66, ww = r - hh * 66;
                int row = hbase + hh - 1, cl = w0 + ww - 1;
                bool ok = ((unsigned)row < 512u) & ((unsigned)cl < 512u);
                int rowc = row < 0 ? 0 : (row > 511 ? 511 : row);
                int clc  = cl  < 0 ? 0 : (cl  > 511 ? 511 : cl);
                const float* src = xb + (size_t)(g * 8) * HW + rowc * WWD + clc;
                #pragma unroll
                for (int j = 0; j < 8; ++j) { float v = src[(size_t)j * HW]; svp[k][j] = ok ? v : 0.f; }
            }
        }
        #pragma unroll
        for (int k = 0; k < 6; ++k) {
            int u = tid + k * 512;
            if (u < 2640) {
                int g = u / 660, p = u - g * 660;
                unsigned q0 = (unsigned)f2bf(svp[k][0]) | ((unsigned)f2bf(svp[k][1]) << 16);
                unsigned q1 = (unsigned)f2bf(svp[k][2]) | ((unsigned)f2bf(svp[k][3]) << 16);
                unsigned q2 = (unsigned)f2bf(svp[k][4]) | ((unsigned)f2bf(svp[k][5]) << 16);
                unsigned q3 = (unsigned)f2bf(svp[k][6]) | ((unsigned)f2bf(svp[k][7]) << 16);
                u32x4 q = { q0, q1, q2, q3 };
                *(u32x4*)(smem + (g * NPIX + p) * 16) = q;
            }
        }
    }

    float svA[5][8], svB[5][8];
    issue8(xb, hbase + 9, w0, svA);    // rows 9..16 (written in body 0)
    __builtin_amdgcn_sched_barrier(0);
    __syncthreads();                   // full drain OK (prologue only)

    int srb = 0;
    // t = 0: cur=svA, issue svB (rows 17..24); svA already landed -> vmcnt(40) no-op
    conv_body<40, 1, 1, 1>(smem, xb, ob, wf, svA, svB, srb, hbase, hbase + 17, w0, wv, col16, g4);
    srb = 8;
    #pragma unroll 1
    for (int tp = 0; tp < 6; ++tp) {
        int t1 = 1 + 2 * tp;
        conv_body<48, 1, 1, 1>(smem, xb, ob, wf, svB, svA, srb,
                               hbase + 8 * t1, hbase + 8 * t1 + 17, w0, wv, col16, g4);
        srb += 8; if (srb >= ROWS) srb -= ROWS;
        conv_body<48, 1, 1, 1>(smem, xb, ob, wf, svA, svB, srb,
                               hbase + 8 * (t1 + 1), hbase + 8 * (t1 + 1) + 17, w0, wv, col16, g4);
        srb += 8; if (srb >= ROWS) srb -= ROWS;
    }
    // t = 13: cur=svB, issue svA (rows 121..128)
    conv_body<48, 1, 1, 1>(smem, xb, ob, wf, svB, svA, srb,
                           hbase + 104, hbase + 121, w0, wv, col16, g4);
    srb += 8; if (srb >= ROWS) srb -= ROWS;
    // t = 14: write svA (rows 121..128), no issue
    conv_body<8, 0, 1, 1>(smem, xb, ob, wf, svA, svB, srb,
                          hbase + 112, 0, w0, wv, col16, g4);
    srb += 8; if (srb >= ROWS) srb -= ROWS;
    // t = 15: compute only
    conv_body<63, 0, 0, 0>(smem, xb, ob, wf, svB, svA, srb,
                           hbase + 120, 0, w0, wv, col16, g4);
}

extern "C" void kernel_launch(void* const* d_in, const int* in_sizes, int n_in,
                              void* d_out, int out_size, void* d_ws, size_t ws_size,
                              hipStream_t stream) {
    const float* x  = (const float*)d_in[0];
    const float* wk = (const float*)d_in[1];
    float* out = (float*)d_out;
    dim3 grid(WWD / TW, HH / (8 * NITER), 16);   // (8, 4, 16) = 512 blocks
    conv3x3_mfma<<<grid, 512, 0, stream>>>(x, wk, out);
}

// Round 6
// 278.422 us; speedup vs baseline: 1.1276x; 1.1276x over previous
//
#include <hip/hip_runtime.h>
#include <hip/hip_bf16.h>

typedef __attribute__((ext_vector_type(8))) short bf16x8;
typedef __attribute__((ext_vector_type(4))) float f32x4;
typedef __attribute__((ext_vector_type(4))) unsigned int u32x4;

#define HH 512
#define WWD 512
#define HW (HH * WWD)
#define TW 64
#define HALO_W 66
#define ROWS 10                 // circular slots: 6 read + 4 write, disjoint
#define NPIX (ROWS * HALO_W)    // 660
#define XBYTES (NPIX * 64)      // 42240
#define WOFF XBYTES
#define WBYTES (9 * 4 * 32 * 16) // 18432
#define DUMMY (WOFF + WBYTES)    // 60672: 1KB per-lane scratch for padded-decode dummies
#define NITER 32                 // 32 * 4 = 128 rows per block

__device__ __forceinline__ unsigned short f2bf(float f) {
    unsigned u = __builtin_bit_cast(unsigned, f);
    u += 0x7FFFu + ((u >> 16) & 1u);
    return (unsigned short)(u >> 16);
}

// uniform 24 loads/thread: 1536 units = (g:4) x (hh:4) x (ww:96, 66 real)
__device__ __forceinline__ void issue4(const float* __restrict__ xb, int row0, int w0,
                                       float (&sv)[3][8]) {
    #pragma unroll
    for (int k = 0; k < 3; ++k) {
        int u = threadIdx.x + k * 512;
        int g = u / 384, r = u - g * 384, hh = r / 96, ww = r - hh * 96;
        int wwc = ww < 66 ? ww : 65;
        int row = row0 + hh, cl = w0 + wwc - 1;
        bool ok = (ww < 66) & ((unsigned)row < 512u) & ((unsigned)cl < 512u);
        int rowc = row < 0 ? 0 : (row > 511 ? 511 : row);
        int clc  = cl  < 0 ? 0 : (cl  > 511 ? 511 : cl);
        const float* src = xb + (size_t)(g * 8) * HW + rowc * WWD + clc;
        #pragma unroll
        for (int j = 0; j < 8; ++j) { float v = src[(size_t)j * HW]; sv[k][j] = ok ? v : 0.f; }
    }
}

__device__ __forceinline__ void write4(char* smem, int wsb, float (&sv)[3][8]) {
    #pragma unroll
    for (int k = 0; k < 3; ++k) {
        int u = threadIdx.x + k * 512;
        int g = u / 384, r = u - g * 384, hh = r / 96, ww = r - hh * 96;
        int slot = wsb + hh; if (slot >= ROWS) slot -= ROWS;
        int byte = (ww < 66) ? (g * NPIX + slot * HALO_W + ww) * 16
                             : (DUMMY + (threadIdx.x & 63) * 16);
        unsigned q0 = (unsigned)f2bf(sv[k][0]) | ((unsigned)f2bf(sv[k][1]) << 16);
        unsigned q1 = (unsigned)f2bf(sv[k][2]) | ((unsigned)f2bf(sv[k][3]) << 16);
        unsigned q2 = (unsigned)f2bf(sv[k][4]) | ((unsigned)f2bf(sv[k][5]) << 16);
        unsigned q3 = (unsigned)f2bf(sv[k][6]) | ((unsigned)f2bf(sv[k][7]) << 16);
        u32x4 q = { q0, q1, q2, q3 };
        *(u32x4*)(smem + byte) = q;
    }
}

template<int WAITN, bool ISS, bool WR, bool BAR>
__device__ __forceinline__ void conv_body(char* smem, const float* __restrict__ xb,
                                          float* __restrict__ ob,
                                          float (&cur)[3][8], float (&nxt)[3][8],
                                          int srb, int rowbase, int issrow, int w0,
                                          int wv, int col16, int g4) {
    if (ISS) {
        issue4(xb, issrow, w0, nxt);   // loads stay in flight across the barrier
        __builtin_amdgcn_sched_barrier(0);
    }
    if constexpr (WAITN == 28) asm volatile("s_waitcnt vmcnt(28)" ::: "memory");
    else if constexpr (WAITN == 4) asm volatile("s_waitcnt vmcnt(4)" ::: "memory");
    if constexpr (WAITN != 63) __builtin_amdgcn_sched_barrier(0);

    if (WR) {   // rows for tile t+1 -> disjoint slots; overlaps MFMAs below
        int wsb = srb + 6; if (wsb >= ROWS) wsb -= ROWS;
        write4(smem, wsb, cur);
    }

    f32x4 acc[2][2];
    {
        f32x4 z = {0.f, 0.f, 0.f, 0.f};
        acc[0][0] = z; acc[0][1] = z; acc[1][0] = z; acc[1][1] = z;
    }
    int rs[3];
    #pragma unroll
    for (int dh = 0; dh < 3; ++dh) {
        int s = srb + (wv >> 1) + dh; if (s >= ROWS) s -= ROWS;
        rs[dh] = s * HALO_W;
    }
    const int wcb = (wv & 1) * 32;
    const char* xg = smem + g4 * (NPIX * 16);
    const char* wg = smem + WOFF + g4 * 512 + col16 * 16;
    #pragma unroll
    for (int dh = 0; dh < 3; ++dh) {
        #pragma unroll
        for (int dw = 0; dw < 3; ++dw) {
            const int tap = dh * 3 + dw;
            bf16x8 b0 = *(const bf16x8*)(wg + tap * 2048);
            bf16x8 b1 = *(const bf16x8*)(wg + tap * 2048 + 256);
            #pragma unroll
            for (int m = 0; m < 2; ++m) {
                bf16x8 a = *(const bf16x8*)(xg + (rs[dh] + wcb + m * 16 + col16 + dw) * 16);
                acc[m][0] = __builtin_amdgcn_mfma_f32_16x16x32_bf16(a, b0, acc[m][0], 0, 0, 0);
                acc[m][1] = __builtin_amdgcn_mfma_f32_16x16x32_bf16(a, b1, acc[m][1], 0, 0, 0);
            }
        }
    }
    {
        float* orow = ob + (size_t)(rowbase + (wv >> 1)) * WWD + w0 + wcb;
        #pragma unroll
        for (int m = 0; m < 2; ++m)
            #pragma unroll
            for (int n = 0; n < 2; ++n)
                *(f32x4*)(orow + (size_t)(n * 16 + col16) * HW + m * 16 + g4 * 4) = acc[m][n];
    }
    if (BAR) {
        asm volatile("s_waitcnt lgkmcnt(0)" ::: "memory");
        __builtin_amdgcn_sched_barrier(0);
        __builtin_amdgcn_s_barrier();
        __builtin_amdgcn_sched_barrier(0);
    }
}

__global__ __launch_bounds__(512, 4)
void conv3x3_mfma(const float* __restrict__ x,
                  const float* __restrict__ wk,
                  float* __restrict__ out) {
    __shared__ __align__(16) char smem[DUMMY + 1024];   // 61696 B -> 2 blocks/CU

    const int tid   = threadIdx.x;
    const int lane  = tid & 63;
    const int wv    = tid >> 6;
    const int col16 = lane & 15;
    const int g4    = lane >> 4;

    const int w0    = blockIdx.x * TW;
    const int hbase = blockIdx.y * (4 * NITER);
    const int b     = blockIdx.z;

    const float* xb = x + (size_t)b * 32 * HW;
    float* ob = out + (size_t)b * 32 * HW;

    // ---- prologue: x rows hbase-1..hbase+4 -> slots 0..5 ----
    float svp[4][8];
    #pragma unroll
    for (int k = 0; k < 4; ++k) {
        int u = tid + k * 512;
        if (u < 1584) {
            int g = u / 396, r = u - g * 396, hh = r / 66, ww = r - hh * 66;
            int row = hbase + hh - 1, cl = w0 + ww - 1;
            bool ok = ((unsigned)row < 512u) & ((unsigned)cl < 512u);
            int rowc = row < 0 ? 0 : (row > 511 ? 511 : row);
            int clc  = cl  < 0 ? 0 : (cl  > 511 ? 511 : cl);
            const float* src = xb + (size_t)(g * 8) * HW + rowc * WWD + clc;
            #pragma unroll
            for (int j = 0; j < 8; ++j) { float v = src[(size_t)j * HW]; svp[k][j] = ok ? v : 0.f; }
        }
    }
    // ---- weights -> LDS bf16, [tap][icg][oc] 16B units (conflict-free reads) ----
    {
        unsigned short* wl = (unsigned short*)(smem + WOFF);
        for (int i = tid; i < 9216; i += 512) {
            int oc = i / 288; int rem = i - oc * 288;
            int ic = rem / 9; int tap = rem - ic * 9;
            wl[((tap * 4 + (ic >> 3)) * 32 + oc) * 8 + (ic & 7)] = f2bf(wk[i]);
        }
    }
    // ---- write prologue x rows ----
    #pragma unroll
    for (int k = 0; k < 4; ++k) {
        int u = tid + k * 512;
        if (u < 1584) {
            int g = u / 396, p = u - g * 396;   // p = hh*66+ww = slot*66+ww directly
            unsigned q0 = (unsigned)f2bf(svp[k][0]) | ((unsigned)f2bf(svp[k][1]) << 16);
            unsigned q1 = (unsigned)f2bf(svp[k][2]) | ((unsigned)f2bf(svp[k][3]) << 16);
            unsigned q2 = (unsigned)f2bf(svp[k][4]) | ((unsigned)f2bf(svp[k][5]) << 16);
            unsigned q3 = (unsigned)f2bf(svp[k][6]) | ((unsigned)f2bf(svp[k][7]) << 16);
            u32x4 q = { q0, q1, q2, q3 };
            *(u32x4*)(smem + (g * NPIX + p) * 16) = q;
        }
    }

    float svA[3][8], svB[3][8];
    issue4(xb, hbase + 5, w0, svA);   // rows 5..8, written during t=0
    __builtin_amdgcn_sched_barrier(0);
    __syncthreads();                  // prologue-only full drain

    int srb = 0;
    // t = 0 (cur=svA already landed; vmcnt(28) trivially true)
    conv_body<28, 1, 1, 1>(smem, xb, ob, svA, svB, srb, hbase, hbase + 9, w0, wv, col16, g4);
    srb = 4;
    #pragma unroll 1
    for (int tp = 0; tp < 14; ++tp) {   // t = 1..28
        int t1 = 1 + 2 * tp;
        conv_body<28, 1, 1, 1>(smem, xb, ob, svB, svA, srb,
                               hbase + 4 * t1, hbase + 4 * t1 + 9, w0, wv, col16, g4);
        srb += 4; if (srb >= ROWS) srb -= ROWS;
        conv_body<28, 1, 1, 1>(smem, xb, ob, svA, svB, srb,
                               hbase + 4 * (t1 + 1), hbase + 4 * (t1 + 1) + 9, w0, wv, col16, g4);
        srb += 4; if (srb >= ROWS) srb -= ROWS;
    }
    // t = 29: issues rows 125..128 into svA
    conv_body<28, 1, 1, 1>(smem, xb, ob, svB, svA, srb, hbase + 116, hbase + 125, w0, wv, col16, g4);
    srb += 4; if (srb >= ROWS) srb -= ROWS;
    // t = 30: write svA (rows 125..128); no issue
    conv_body<4, 0, 1, 1>(smem, xb, ob, svA, svB, srb, hbase + 120, 0, w0, wv, col16, g4);
    srb += 4; if (srb >= ROWS) srb -= ROWS;
    // t = 31: compute only
    conv_body<63, 0, 0, 0>(smem, xb, ob, svB, svA, srb, hbase + 124, 0, w0, wv, col16, g4);
}

extern "C" void kernel_launch(void* const* d_in, const int* in_sizes, int n_in,
                              void* d_out, int out_size, void* d_ws, size_t ws_size,
                              hipStream_t stream) {
    const float* x  = (const float*)d_in[0];
    const float* wk = (const float*)d_in[1];
    float* out = (float*)d_out;
    dim3 grid(WWD / TW, HH / (4 * NITER), 16);   // (8, 4, 16) = 512 blocks, 2/CU
    conv3x3_mfma<<<grid, 512, 0, stream>>>(x, wk, out);
}